// Round 1
// baseline (347.191 us; speedup 1.0000x reference)
//
#include <hip/hip_runtime.h>

#define H 16
#define MH 64
#define LN_EPS 1e-5f

// ---------- small fused helpers (all register-resident, all index-constant) ----------

__device__ __forceinline__ void encode5(const float xin[5],
    const float* __restrict__ w1, const float* __restrict__ b1,
    const float* __restrict__ w2, const float* __restrict__ b2,
    float hout[H])
{
    float t[H];
#pragma unroll
    for (int j = 0; j < H; ++j) {
        float s = b1[j];
#pragma unroll
        for (int k = 0; k < 5; ++k) s = fmaf(xin[k], w1[k * H + j], s);
        t[j] = fmaxf(s, 0.f);
    }
#pragma unroll
    for (int j = 0; j < H; ++j) hout[j] = b2[j];
#pragma unroll
    for (int k = 0; k < H; ++k) {
        float tk = t[k];
#pragma unroll
        for (int j = 0; j < H; ++j) hout[j] = fmaf(tk, w2[k * H + j], hout[j]);
    }
}

// One GINEConv + MLP + LayerNorm + ReLU block, updating h[4][H] in place.
__device__ __forceinline__ void gine_block(
    float (*h)[H], const float4* __restrict__ eg4,
    const float* __restrict__ lw, const float* __restrict__ lb,
    const float* __restrict__ w1, const float* __restrict__ b1,
    const float* __restrict__ w2, const float* __restrict__ b2)
{
    // u[t] = h[t] + sum_{s != t} relu(h[s] + Lin(edge_attr[e(s,t)]))
    float u[4][H];
#pragma unroll
    for (int t = 0; t < 4; ++t)
#pragma unroll
        for (int j = 0; j < H; ++j) u[t][j] = h[t][j];

#pragma unroll
    for (int s = 0; s < 4; ++s) {
#pragma unroll
        for (int t = 0; t < 4; ++t) {
            if (t == s) continue;
            const int e = s * 3 + (t < s ? t : t - 1);  // pair order (i,j), j ascending skipping i
            const float4 ea = eg4[e];
#pragma unroll
            for (int j = 0; j < H; ++j) {
                float lv = lb[j];
                lv = fmaf(ea.x, lw[0 * H + j], lv);
                lv = fmaf(ea.y, lw[1 * H + j], lv);
                lv = fmaf(ea.z, lw[2 * H + j], lv);
                lv = fmaf(ea.w, lw[3 * H + j], lv);
                u[t][j] += fmaxf(h[s][j] + lv, 0.f);
            }
        }
    }

    // per-node MLP 16->64->16, then LayerNorm + ReLU, write back into h[t]
#pragma unroll
    for (int t = 0; t < 4; ++t) {
        float o[H];
#pragma unroll
        for (int j = 0; j < H; ++j) o[j] = b2[j];
#pragma unroll 4
        for (int k = 0; k < MH; ++k) {
            float s = b1[k];
#pragma unroll
            for (int j = 0; j < H; ++j) s = fmaf(u[t][j], w1[j * MH + k], s);
            s = fmaxf(s, 0.f);
#pragma unroll
            for (int j = 0; j < H; ++j) o[j] = fmaf(s, w2[k * H + j], o[j]);
        }
        float m = 0.f;
#pragma unroll
        for (int j = 0; j < H; ++j) m += o[j];
        m *= (1.f / H);
        float v = 0.f;
#pragma unroll
        for (int j = 0; j < H; ++j) { float d = o[j] - m; v = fmaf(d, d, v); }
        v *= (1.f / H);
        const float r = rsqrtf(v + LN_EPS);
#pragma unroll
        for (int j = 0; j < H; ++j) h[t][j] = fmaxf((o[j] - m) * r, 0.f);
    }
}

__global__ __launch_bounds__(256) void gnn_fused_kernel(
    const float* __restrict__ x,          // [N,5]
    const float* __restrict__ edge_attr,  // [E,4]
    const float* __restrict__ je_w1, const float* __restrict__ je_b1,
    const float* __restrict__ je_w2, const float* __restrict__ je_b2,
    const float* __restrict__ mu_w1, const float* __restrict__ mu_b1,
    const float* __restrict__ mu_w2, const float* __restrict__ mu_b2,
    const float* __restrict__ l1w, const float* __restrict__ l1b,
    const float* __restrict__ m1w1, const float* __restrict__ m1b1,
    const float* __restrict__ m1w2, const float* __restrict__ m1b2,
    const float* __restrict__ l2w, const float* __restrict__ l2b,
    const float* __restrict__ m2w1, const float* __restrict__ m2b1,
    const float* __restrict__ m2w2, const float* __restrict__ m2b2,
    const float* __restrict__ fcw1, const float* __restrict__ fcb1,
    const float* __restrict__ fcw2, const float* __restrict__ fcb2,
    float* __restrict__ out, int nG)
{
    const int g = blockIdx.x * blockDim.x + threadIdx.x;
    if (g >= nG) return;

    // ---- load node features: 4 nodes x 5 feats = 5 aligned float4s ----
    const float4* xg4 = (const float4*)x + (size_t)g * 5;
    const float4 a0 = xg4[0], a1 = xg4[1], a2 = xg4[2], a3 = xg4[3], a4 = xg4[4];
    const float xin[4][5] = {
        {a0.x, a0.y, a0.z, a0.w, a1.x},
        {a1.y, a1.z, a1.w, a2.x, a2.y},
        {a2.z, a2.w, a3.x, a3.y, a3.z},
        {a3.w, a4.x, a4.y, a4.z, a4.w}};

    const float4* eg4 = (const float4*)edge_attr + (size_t)g * 12;

    // ---- heterogeneous encoders: nodes 0..2 jet (type 0), node 3 muon (type 1) ----
    float h[4][H];
    encode5(xin[0], je_w1, je_b1, je_w2, je_b2, h[0]);
    encode5(xin[1], je_w1, je_b1, je_w2, je_b2, h[1]);
    encode5(xin[2], je_w1, je_b1, je_w2, je_b2, h[2]);
    encode5(xin[3], mu_w1, mu_b1, mu_w2, mu_b2, h[3]);

    // ---- two GINE blocks (each: conv + MLP + LN + ReLU) ----
    gine_block(h, eg4, l1w, l1b, m1w1, m1b1, m1w2, m1b2);
    gine_block(h, eg4, l2w, l2b, m2w1, m2b1, m2w2, m2b2);

    // ---- pooling: mean + max over the 4 nodes, concat -> [32] ----
    float c[2 * H];
#pragma unroll
    for (int j = 0; j < H; ++j) {
        const float s0 = h[0][j], s1 = h[1][j], s2 = h[2][j], s3 = h[3][j];
        c[j] = (s0 + s1 + s2 + s3) * 0.25f;
        c[H + j] = fmaxf(fmaxf(s0, s1), fmaxf(s2, s3));
    }

    // ---- LayerNorm over 32 ----
    float m = 0.f;
#pragma unroll
    for (int j = 0; j < 2 * H; ++j) m += c[j];
    m *= (1.f / (2 * H));
    float v = 0.f;
#pragma unroll
    for (int j = 0; j < 2 * H; ++j) { float d = c[j] - m; v = fmaf(d, d, v); }
    v *= (1.f / (2 * H));
    const float r = rsqrtf(v + LN_EPS);
#pragma unroll
    for (int j = 0; j < 2 * H; ++j) c[j] = (c[j] - m) * r;

    // ---- fc: 32 -> 64 -> 1 ----
    float acc = fcb2[0];
#pragma unroll 4
    for (int k = 0; k < MH; ++k) {
        float s = fcb1[k];
#pragma unroll
        for (int j = 0; j < 2 * H; ++j) s = fmaf(c[j], fcw1[j * MH + k], s);
        acc = fmaf(fmaxf(s, 0.f), fcw2[k], acc);
    }

    out[g] = acc;
}

extern "C" void kernel_launch(void* const* d_in, const int* in_sizes, int n_in,
                              void* d_out, int out_size, void* d_ws, size_t ws_size,
                              hipStream_t stream) {
    const float* x         = (const float*)d_in[0];
    const float* edge_attr = (const float*)d_in[1];
    const float* je_w1 = (const float*)d_in[2];
    const float* je_b1 = (const float*)d_in[3];
    const float* je_w2 = (const float*)d_in[4];
    const float* je_b2 = (const float*)d_in[5];
    const float* mu_w1 = (const float*)d_in[6];
    const float* mu_b1 = (const float*)d_in[7];
    const float* mu_w2 = (const float*)d_in[8];
    const float* mu_b2 = (const float*)d_in[9];
    const float* l1w   = (const float*)d_in[10];
    const float* l1b   = (const float*)d_in[11];
    const float* m1w1  = (const float*)d_in[12];
    const float* m1b1  = (const float*)d_in[13];
    const float* m1w2  = (const float*)d_in[14];
    const float* m1b2  = (const float*)d_in[15];
    const float* l2w   = (const float*)d_in[16];
    const float* l2b   = (const float*)d_in[17];
    const float* m2w1  = (const float*)d_in[18];
    const float* m2b1  = (const float*)d_in[19];
    const float* m2w2  = (const float*)d_in[20];
    const float* m2b2  = (const float*)d_in[21];
    const float* fcw1  = (const float*)d_in[22];
    const float* fcb1  = (const float*)d_in[23];
    const float* fcw2  = (const float*)d_in[24];
    const float* fcb2  = (const float*)d_in[25];
    // d_in[26]=type_id, d_in[27]=edge_index, d_in[28]=batch, d_in[29]=num_graphs:
    // the graph topology / typing is static (4 nodes, 12 fixed edges, [0,0,0,1]) — not read.

    const int nG = out_size;  // one scalar per graph
    const int threads = 256;
    const int blocks = (nG + threads - 1) / threads;
    gnn_fused_kernel<<<blocks, threads, 0, stream>>>(
        x, edge_attr,
        je_w1, je_b1, je_w2, je_b2,
        mu_w1, mu_b1, mu_w2, mu_b2,
        l1w, l1b, m1w1, m1b1, m1w2, m1b2,
        l2w, l2b, m2w1, m2b1, m2w2, m2b2,
        fcw1, fcb1, fcw2, fcb2,
        (float*)d_out, nG);
}

// Round 2
// 303.302 us; speedup vs baseline: 1.1447x; 1.1447x over previous
//
#include <hip/hip_runtime.h>

#define H 16
#define MH 64
#define LN_EPS 1e-5f

// One NODE per lane. Lanes 4q..4q+3 of a wave hold the 4 nodes of graph
// (gbase + q). Messages & pooling use quad __shfl_xor (masks 1..3).
// fc head is re-partitioned via LDS so its weights stay wave-uniform.

__device__ __forceinline__ void encode5_lane(const float xin[5],
    const float* __restrict__ w1, const float* __restrict__ b1,
    const float* __restrict__ w2, const float* __restrict__ b2,
    float hout[H])
{
    float t[H];
#pragma unroll
    for (int j = 0; j < H; ++j) {
        float s = b1[j];
#pragma unroll
        for (int k = 0; k < 5; ++k) s = fmaf(xin[k], w1[k * H + j], s);
        t[j] = fmaxf(s, 0.f);
    }
#pragma unroll
    for (int j = 0; j < H; ++j) hout[j] = b2[j];
#pragma unroll
    for (int k = 0; k < H; ++k) {
        const float tk = t[k];
#pragma unroll
        for (int j = 0; j < H; ++j) hout[j] = fmaf(tk, w2[k * H + j], hout[j]);
    }
}

// GINEConv + MLP + LN + ReLU for THIS lane's node; h updated in place.
__device__ __forceinline__ void gine_block_lane(float h[H], const float4 ea[3],
    const float* __restrict__ lw, const float* __restrict__ lb,
    const float* __restrict__ w1, const float* __restrict__ b1,
    const float* __restrict__ w2, const float* __restrict__ b2)
{
    float u[H];
#pragma unroll
    for (int j = 0; j < H; ++j) u[j] = h[j];

    // sum over the 3 sources s = t^m (quad shuffles)
#pragma unroll
    for (int m = 1; m <= 3; ++m) {
        const float4 e = ea[m - 1];
#pragma unroll
        for (int j = 0; j < H; ++j) {
            const float hs = __shfl_xor(h[j], m, 64);
            float lv = lb[j];
            lv = fmaf(e.x, lw[0 * H + j], lv);
            lv = fmaf(e.y, lw[1 * H + j], lv);
            lv = fmaf(e.z, lw[2 * H + j], lv);
            lv = fmaf(e.w, lw[3 * H + j], lv);
            u[j] += fmaxf(hs + lv, 0.f);
        }
    }

    // MLP 16 -> 64 -> 16 (weights wave-uniform -> scalar loads)
    float o[H];
#pragma unroll
    for (int j = 0; j < H; ++j) o[j] = b2[j];
#pragma unroll 4
    for (int k = 0; k < MH; ++k) {
        float s = b1[k];
#pragma unroll
        for (int j = 0; j < H; ++j) s = fmaf(u[j], w1[j * MH + k], s);
        s = fmaxf(s, 0.f);
#pragma unroll
        for (int j = 0; j < H; ++j) o[j] = fmaf(s, w2[k * H + j], o[j]);
    }

    // LayerNorm over 16 + ReLU
    float m = 0.f;
#pragma unroll
    for (int j = 0; j < H; ++j) m += o[j];
    m *= (1.f / H);
    float v = 0.f;
#pragma unroll
    for (int j = 0; j < H; ++j) { const float d = o[j] - m; v = fmaf(d, d, v); }
    v *= (1.f / H);
    const float r = rsqrtf(v + LN_EPS);
#pragma unroll
    for (int j = 0; j < H; ++j) h[j] = fmaxf((o[j] - m) * r, 0.f);
}

__global__ __launch_bounds__(256) void gnn_npl_kernel(
    const float* __restrict__ x,          // [N,5]
    const float* __restrict__ edge_attr,  // [E,4]
    const float* __restrict__ je_w1, const float* __restrict__ je_b1,
    const float* __restrict__ je_w2, const float* __restrict__ je_b2,
    const float* __restrict__ mu_w1, const float* __restrict__ mu_b1,
    const float* __restrict__ mu_w2, const float* __restrict__ mu_b2,
    const float* __restrict__ l1w, const float* __restrict__ l1b,
    const float* __restrict__ m1w1, const float* __restrict__ m1b1,
    const float* __restrict__ m1w2, const float* __restrict__ m1b2,
    const float* __restrict__ l2w, const float* __restrict__ l2b,
    const float* __restrict__ m2w1, const float* __restrict__ m2b1,
    const float* __restrict__ m2w2, const float* __restrict__ m2b2,
    const float* __restrict__ fcw1, const float* __restrict__ fcb1,
    const float* __restrict__ fcw2, const float* __restrict__ fcb2,
    float* __restrict__ out, int nG)
{
    __shared__ float lds_c[64 * 33];   // [graph-in-block][32 + 1 pad]
    __shared__ float lds_p[256];       // fc partials [wave][graph]

    const int tIdx = threadIdx.x;
    const int qb   = tIdx >> 2;        // graph index within block [0,64)
    const int t    = tIdx & 3;         // node within graph
    const int gbase = blockIdx.x * 64;
    int g = gbase + qb;
    if (g >= nG) g = nG - 1;           // clamp: loads stay valid, store is guarded
    const int node = g * 4 + t;

    // ---- node features (5 scalar loads; memory is ~2% of peak, fine) ----
    float xin[5];
#pragma unroll
    for (int i = 0; i < 5; ++i) xin[i] = x[node * 5 + i];

    // ---- 3 incoming edges, ordered by xor mask m (source s = t^m) ----
    float4 ea[3];
#pragma unroll
    for (int m = 1; m <= 3; ++m) {
        const int s = t ^ m;
        const int el = s * 3 + (t < s ? t : t - 1);  // pair (i,j) enumeration
        ea[m - 1] = ((const float4*)edge_attr)[g * 12 + el];
    }

    // ---- hetero encoders: compute both, select (node 3 = muon) ----
    float h[H], hj[H], hm[H];
    encode5_lane(xin, je_w1, je_b1, je_w2, je_b2, hj);
    encode5_lane(xin, mu_w1, mu_b1, mu_w2, mu_b2, hm);
#pragma unroll
    for (int j = 0; j < H; ++j) h[j] = (t == 3) ? hm[j] : hj[j];

    // ---- two GINE blocks ----
    gine_block_lane(h, ea, l1w, l1b, m1w1, m1b1, m1w2, m1b2);
    gine_block_lane(h, ea, l2w, l2b, m2w1, m2b1, m2w2, m2b2);

    // ---- pooling: quad butterfly sum & max ----
    float c[2 * H];
#pragma unroll
    for (int j = 0; j < H; ++j) {
        float sm = h[j], mx = h[j];
        {
            const float o1 = __shfl_xor(sm, 1, 64);
            sm += o1; mx = fmaxf(mx, o1);
        }
        {
            const float o2s = __shfl_xor(sm, 2, 64);
            const float o2m = __shfl_xor(mx, 2, 64);
            sm += o2s; mx = fmaxf(mx, o2m);
        }
        c[j] = sm * 0.25f;
        c[H + j] = mx;
    }

    // ---- LayerNorm over 32 (each quad lane redundantly; cheap) ----
    float m = 0.f;
#pragma unroll
    for (int j = 0; j < 2 * H; ++j) m += c[j];
    m *= (1.f / (2 * H));
    float v = 0.f;
#pragma unroll
    for (int j = 0; j < 2 * H; ++j) { const float d = c[j] - m; v = fmaf(d, d, v); }
    v *= (1.f / (2 * H));
    const float r = rsqrtf(v + LN_EPS);
#pragma unroll
    for (int j = 0; j < 2 * H; ++j) c[j] = (c[j] - m) * r;

    // ---- stash normalized c: lane t writes its 8-float slice ----
#pragma unroll
    for (int i = 0; i < 8; ++i) lds_c[qb * 33 + t * 8 + i] = c[t * 8 + i];
    __syncthreads();

    // ---- fc 32->64->1, re-partitioned: wave w does k in [16w,16w+16)
    //      for ALL 64 graphs of the block (k wave-uniform -> s_loads) ----
    const int wv   = tIdx >> 6;   // wave id 0..3
    const int lane = tIdx & 63;   // graph-in-block for this phase
    float cc[2 * H];
#pragma unroll
    for (int j = 0; j < 2 * H; ++j) cc[j] = lds_c[lane * 33 + j];
    float acc = 0.f;
#pragma unroll 4
    for (int kk = 0; kk < 16; ++kk) {
        const int k = wv * 16 + kk;
        float s = fcb1[k];
#pragma unroll
        for (int j = 0; j < 2 * H; ++j) s = fmaf(cc[j], fcw1[j * MH + k], s);
        acc = fmaf(fmaxf(s, 0.f), fcw2[k], acc);
    }
    lds_p[wv * 64 + lane] = acc;
    __syncthreads();

    if (tIdx < 64) {
        const int gq = gbase + tIdx;
        if (gq < nG)
            out[gq] = fcb2[0] + lds_p[tIdx] + lds_p[64 + tIdx] +
                      lds_p[128 + tIdx] + lds_p[192 + tIdx];
    }
}

extern "C" void kernel_launch(void* const* d_in, const int* in_sizes, int n_in,
                              void* d_out, int out_size, void* d_ws, size_t ws_size,
                              hipStream_t stream) {
    const float* x         = (const float*)d_in[0];
    const float* edge_attr = (const float*)d_in[1];
    const float* je_w1 = (const float*)d_in[2];
    const float* je_b1 = (const float*)d_in[3];
    const float* je_w2 = (const float*)d_in[4];
    const float* je_b2 = (const float*)d_in[5];
    const float* mu_w1 = (const float*)d_in[6];
    const float* mu_b1 = (const float*)d_in[7];
    const float* mu_w2 = (const float*)d_in[8];
    const float* mu_b2 = (const float*)d_in[9];
    const float* l1w   = (const float*)d_in[10];
    const float* l1b   = (const float*)d_in[11];
    const float* m1w1  = (const float*)d_in[12];
    const float* m1b1  = (const float*)d_in[13];
    const float* m1w2  = (const float*)d_in[14];
    const float* m1b2  = (const float*)d_in[15];
    const float* l2w   = (const float*)d_in[16];
    const float* l2b   = (const float*)d_in[17];
    const float* m2w1  = (const float*)d_in[18];
    const float* m2b1  = (const float*)d_in[19];
    const float* m2w2  = (const float*)d_in[20];
    const float* m2b2  = (const float*)d_in[21];
    const float* fcw1  = (const float*)d_in[22];
    const float* fcb1  = (const float*)d_in[23];
    const float* fcw2  = (const float*)d_in[24];
    const float* fcb2  = (const float*)d_in[25];
    // type_id / edge_index / batch / num_graphs are static topology — not read.

    const int nG = out_size;
    const int blocks = (nG + 63) / 64;   // 64 graphs (256 nodes) per block
    gnn_npl_kernel<<<blocks, 256, 0, stream>>>(
        x, edge_attr,
        je_w1, je_b1, je_w2, je_b2,
        mu_w1, mu_b1, mu_w2, mu_b2,
        l1w, l1b, m1w1, m1b1, m1w2, m1b2,
        l2w, l2b, m2w1, m2b1, m2w2, m2b2,
        fcw1, fcb1, fcw2, fcb2,
        (float*)d_out, nG);
}